// Round 13
// baseline (441.278 us; speedup 1.0000x reference)
//
#include <hip/hip_runtime.h>

#define NT 10          // trees
#define NL 16          // leaves per tree
#define NN 31          // nodes per tree
#define DD 256         // hidden dim
#define G4 1024        // 4*D gates
#define NNODES (NT*NN) // 310
#define NB 4096

__device__ __forceinline__ float sigf(float x)   { return 1.0f / (1.0f + __expf(-x)); }
__device__ __forceinline__ float tanh_f(float x) { return 2.0f / (1.0f + __expf(-2.0f*x)) - 1.0f; }

// ---------------------------------------------------------------------------
// K1: nodeproj. xg[n][j] = emb[n].Wih[j] + bih[j] + bhh[j]
// 256 blocks = (mt 0..15 [20 nodes]) x (nt 0..15 [64 W rows]). Proven ~3 us.
// Plain stores; the launch boundary publishes xg to K2.
// ---------------------------------------------------------------------------
__global__ __launch_bounds__(256) void k_nodeproj(
    const float* __restrict__ emb, const float* __restrict__ Wih,
    const float* __restrict__ bih, const float* __restrict__ bhh,
    float* __restrict__ xg)
{
    __shared__ float smem[20 * 260 + 20 * 4 * 64];
    float4* es4 = (float4*)smem;
    float*  ps  = smem + 20 * 260;

    const int tid = threadIdx.x;
    const int nt  = blockIdx.x & 15;
    const int mt  = blockIdx.x >> 4;
    const int kq  = tid >> 6;
    const int w   = tid & 63;

    const float4* W4 = (const float4*)Wih + (size_t)(nt * 64 + w) * 64 + kq * 16;
    float4 wr[16];
    #pragma unroll
    for (int j = 0; j < 16; ++j) wr[j] = W4[j];

    const float4* emb4 = (const float4*)emb;
    #pragma unroll
    for (int r = 0; r < 5; ++r) {
        int idx = tid + 256 * r;                  // 0..1279
        int m = idx >> 6, q = idx & 63;
        int n = mt * 20 + m;
        es4[m * 65 + q] = (n < NNODES) ? emb4[(size_t)n * 64 + q]
                                       : make_float4(0.f, 0.f, 0.f, 0.f);
    }
    __syncthreads();

    float acc[20];
    #pragma unroll
    for (int m = 0; m < 20; ++m) acc[m] = 0.f;
    #pragma unroll
    for (int j = 0; j < 16; ++j) {
        float4 wv = wr[j];
        #pragma unroll
        for (int m = 0; m < 20; ++m) {
            float4 h = es4[m * 65 + kq * 16 + j];
            acc[m] = fmaf(wv.x, h.x, fmaf(wv.y, h.y,
                     fmaf(wv.z, h.z, fmaf(wv.w, h.w, acc[m]))));
        }
    }
    #pragma unroll
    for (int m = 0; m < 20; ++m) ps[(m * 4 + kq) * 64 + w] = acc[m];
    __syncthreads();

    const int nl   = tid & 63;
    const int msub = tid >> 6;
    const int j    = nt * 64 + nl;
    const float bsum = bih[j] + bhh[j];
    #pragma unroll
    for (int r = 0; r < 5; ++r) {
        int m = msub * 5 + r;
        int n = mt * 20 + m;
        float s = ps[(m * 4 + 0) * 64 + nl] + ps[(m * 4 + 1) * 64 + nl]
                + ps[(m * 4 + 2) * 64 + nl] + ps[(m * 4 + 3) * 64 + nl];
        if (n < NNODES) xg[(size_t)n * G4 + j] = s + bsum;
    }
}

// ---------------------------------------------------------------------------
// K2: MONOLITHIC tree-LSTM — one block per tree, ZERO cross-block sync.
// 10 blocks x 1024 threads. Thread (d = tid>>2, q = tid&3) holds quarter q
// of the 4 gate-rows {g*256+d} of W_hh register-stationary (64 float4 =
// 256 VGPRs; 4 waves/SIMD x ~300 VGPR fits the 2048/SIMD file).
// Per parent p: 4 quarter-dots vs h[p] (LDS, 4-way multicast reads), fold
// across the 4-lane group via __shfl_xor(1|2), lanes q<2 finish child 2p+q:
// gates + xg row loads -> c,h into LDS ping-pong. One __syncthreads per
// step. 15 parent-GEMMs = 3.93M FMA/tree = ~13 us on one CU -- cheaper than
// the ~28 us of mechanism-invariant cross-block rounds it replaces (R2-R12).
// ---------------------------------------------------------------------------
__global__ __launch_bounds__(1024, 1) void k_monolstm(
    const float* __restrict__ xg, const float* __restrict__ Whh,
    float* __restrict__ h4g)
{
    __shared__ float hsA[8 * DD], hsB[8 * DD];   // h ping-pong (<=8 rows)
    __shared__ float clA[8 * DD], clB[8 * DD];   // c ping-pong (<=8 rows)

    const int tid = threadIdx.x;
    const int t   = blockIdx.x;        // tree
    const int d   = tid >> 2;          // output col 0..255
    const int q   = tid & 3;           // reduction quarter

    // ---- W_hh quarter-rows for all 4 gates of col d -> 256 VGPRs
    const float4* W4 = (const float4*)Whh;
    float4 w0[16], w1[16], w2[16], w3[16];
    #pragma unroll
    for (int j = 0; j < 16; ++j) {
        w0[j] = W4[(size_t)(          d) * 64 + q * 16 + j];
        w1[j] = W4[(size_t)(256     + d) * 64 + q * 16 + j];
        w2[j] = W4[(size_t)(512     + d) * 64 + q * 16 + j];
        w3[j] = W4[(size_t)(768     + d) * 64 + q * 16 + j];
    }

    // ---- root step: elementwise from xg[node 0] (h(-1)=c(-1)=0)
    const float* xr = xg + (size_t)t * NN * G4;
    if (q == 0) {
        float xi  = xr[d];
        float xgg = xr[512 + d];
        float xo  = xr[768 + d];
        float c0 = sigf(xi) * tanh_f(xgg);
        hsA[d] = sigf(xo) * tanh_f(c0);
        clA[d] = c0;
    }
    __syncthreads();

    float* hsP = hsA; float* hsC = hsB;
    float* clP = clA; float* clC = clB;

    #pragma unroll
    for (int s = 1; s <= 4; ++s) {
        const int L = 1 << (s - 1);              // parents this step

        #pragma unroll
        for (int p = 0; p < L; ++p) {
            // quarter-dots: <W[g][q-quarter], h[p][q-quarter]>
            const float4* hp = (const float4*)(hsP + p * DD) + q * 16;
            float4 a0 = make_float4(0.f, 0.f, 0.f, 0.f);
            float4 a1 = a0, a2 = a0, a3 = a0;
            #pragma unroll
            for (int j = 0; j < 16; ++j) {
                float4 hv = hp[j];               // 4-way multicast LDS read
                a0.x = fmaf(w0[j].x, hv.x, a0.x); a0.y = fmaf(w0[j].y, hv.y, a0.y);
                a0.z = fmaf(w0[j].z, hv.z, a0.z); a0.w = fmaf(w0[j].w, hv.w, a0.w);
                a1.x = fmaf(w1[j].x, hv.x, a1.x); a1.y = fmaf(w1[j].y, hv.y, a1.y);
                a1.z = fmaf(w1[j].z, hv.z, a1.z); a1.w = fmaf(w1[j].w, hv.w, a1.w);
                a2.x = fmaf(w2[j].x, hv.x, a2.x); a2.y = fmaf(w2[j].y, hv.y, a2.y);
                a2.z = fmaf(w2[j].z, hv.z, a2.z); a2.w = fmaf(w2[j].w, hv.w, a2.w);
                a3.x = fmaf(w3[j].x, hv.x, a3.x); a3.y = fmaf(w3[j].y, hv.y, a3.y);
                a3.z = fmaf(w3[j].z, hv.z, a3.z); a3.w = fmaf(w3[j].w, hv.w, a3.w);
            }
            float g0 = (a0.x + a0.y) + (a0.z + a0.w);
            float g1 = (a1.x + a1.y) + (a1.z + a1.w);
            float g2 = (a2.x + a2.y) + (a2.z + a2.w);
            float g3 = (a3.x + a3.y) + (a3.z + a3.w);
            // fold the 4 quarters across the 4-lane group (all lanes get sum)
            g0 += __shfl_xor(g0, 1); g0 += __shfl_xor(g0, 2);
            g1 += __shfl_xor(g1, 1); g1 += __shfl_xor(g1, 2);
            g2 += __shfl_xor(g2, 1); g2 += __shfl_xor(g2, 2);
            g3 += __shfl_xor(g3, 1); g3 += __shfl_xor(g3, 2);

            // epilogue: lane q handles child 2p+q (q<2); dot shared by both
            if (q < 2) {
                const int child = 2 * p + q;
                const int node  = (1 << s) - 1 + child;
                const float* xn = xg + ((size_t)t * NN + node) * G4;
                float gi = g0 + xn[      d];
                float gf = g1 + xn[256 + d];
                float gg = g2 + xn[512 + d];
                float go = g3 + xn[768 + d];
                float cin = clP[p * DD + d];
                float cn  = sigf(gf) * cin + sigf(gi) * tanh_f(gg);
                float hn  = sigf(go) * tanh_f(cn);
                if (s < 4) {
                    hsC[child * DD + d] = hn;
                    clC[child * DD + d] = cn;
                } else {
                    // launch boundary publishes h4 to the scatter kernel
                    h4g[((size_t)t * NL + child) * DD + d] = hn;
                }
            }
        }
        __syncthreads();                         // children visible block-wide
        float* tp;
        tp = hsP; hsP = hsC; hsC = tp;
        tp = clP; clP = clC; clC = tp;
    }
}

// ---------------------------------------------------------------------------
// K3: scatter out[b,t,:] = h4[t*16 + argmax(cross[b,t,:]), :]
// One wave per (b,t) row (40960 waves): ballot -> leaf, float4 row copy.
// (Proven R2/R7/R10 version.)
// ---------------------------------------------------------------------------
__global__ __launch_bounds__(256) void k_scatter(
    const float* __restrict__ cross, const float* __restrict__ htab,
    float* __restrict__ out)
{
    const int tid  = threadIdx.x;
    const int wave = tid >> 6;
    const int lane = tid & 63;
    const int r = blockIdx.x * 4 + wave;     // 0..40959 = b*10 + t
    const int b = r / NT;
    const int t = r - b * NT;

    float v = 0.f;
    if (lane < NL) v = cross[(size_t)b * (NT * NL) + t * NL + lane];
    unsigned long long m = __ballot(v > 0.5f);
    int leaf = m ? (int)__builtin_ctzll(m) : 0;
    int p = t * NL + leaf;

    const float4* h4 = (const float4*)htab;
    float4* o4 = (float4*)out;
    o4[(size_t)r * 64 + lane] = h4[(size_t)p * 64 + lane];
}

// ---------------------------------------------------------------------------
extern "C" void kernel_launch(void* const* d_in, const int* in_sizes, int n_in,
                              void* d_out, int out_size, void* d_ws, size_t ws_size,
                              hipStream_t stream)
{
    const float* cross = (const float*)d_in[0];
    const float* emb   = (const float*)d_in[1];
    const float* Wih   = (const float*)d_in[2];
    const float* Whh   = (const float*)d_in[3];
    const float* bih   = (const float*)d_in[4];
    const float* bhh   = (const float*)d_in[5];
    float* out = (float*)d_out;

    float* ws  = (float*)d_ws;
    float* xg  = ws;                         // 310*1024
    float* h4g = xg + (size_t)NNODES * G4;   // 160*256

    hipLaunchKernelGGL(k_nodeproj, dim3(256), dim3(256), 0, stream,
                       emb, Wih, bih, bhh, xg);
    hipLaunchKernelGGL(k_monolstm, dim3(NT), dim3(1024), 0, stream,
                       xg, Whh, h4g);
    hipLaunchKernelGGL(k_scatter, dim3(10240), dim3(256), 0, stream,
                       cross, h4g, out);
}

// Round 14
// 100.224 us; speedup vs baseline: 4.4029x; 4.4029x over previous
//
#include <hip/hip_runtime.h>

#define NT 10          // trees
#define NL 16          // leaves per tree
#define NN 31          // nodes per tree
#define DD 256         // hidden dim
#define NB 4096

// Per-block private launch-generation counters (zero-init at module load;
// __device__ space survives ws poison). Block (t,dt) alone reads+bumps its
// word at entry: read-before-bump => G = #completed launches, identical
// across all blocks of a launch, dispatch-order- and graph-replay-safe.
// tag = G+1 (1,2,3,...) can never equal ws-poison 0xAAAAAAAA.
__device__ unsigned g_gen[NT * 16];

__device__ __forceinline__ float sigf(float x)   { return 1.0f / (1.0f + __expf(-x)); }
__device__ __forceinline__ float tanh_f(float x) { return 2.0f / (1.0f + __expf(-2.0f*x)) - 1.0f; }

// Gen-tagged word publish/poll (proven R9/R10): datum + readiness in ONE
// aligned 8-byte atomic word => no flag round, no fences; sync cost = one
// store->load visibility hop, per-word skew absorption.
__device__ __forceinline__ void pub64(unsigned long long* p, unsigned tag, float v) {
    union { float f; unsigned u; } c; c.f = v;
    __hip_atomic_store(p, ((unsigned long long)tag << 32) | c.u,
                       __ATOMIC_RELAXED, __HIP_MEMORY_SCOPE_AGENT);
}
__device__ __forceinline__ unsigned long long ld64(const unsigned long long* p) {
    return __hip_atomic_load(p, __ATOMIC_RELAXED, __HIP_MEMORY_SCOPE_AGENT);
}
__device__ __forceinline__ float payload(unsigned long long w) {
    union { unsigned u; float f; } c; c.u = (unsigned)w; return c.f;
}

// ---------------------------------------------------------------------------
// K1: whole tree-LSTM, 160 blocks = 10 trees x 16 d-tiles (R10 verbatim —
// proven 101.3us config). Interleaved xproj schedule:
//   entry -> x[0] -> root+pub(h0) -> x[1..6] -> stage h0 -> s1 -> pub(h1)
//   -> x[7..14] -> stage h1 -> s2 -> pub(h2) -> x[15..22] -> stage h2 -> s3
//   -> pub(h3) -> x[23..30] -> stage h3 -> s4 -> h4 store (launch boundary).
// ---------------------------------------------------------------------------
__global__ __launch_bounds__(256) void k_treelstm(
    const float* __restrict__ emb, const float* __restrict__ Wih,
    const float* __restrict__ Whh, const float* __restrict__ bih,
    const float* __restrict__ bhh,
    unsigned long long* __restrict__ hx0, unsigned long long* __restrict__ hx1,
    unsigned long long* __restrict__ hx2, unsigned long long* __restrict__ hx3,
    float* __restrict__ h4g)
{
    __shared__ float es [NN * DD];     // 31 emb rows (tree-local)
    __shared__ float ps [8 * DD];      // GEMM partials (4 quarters x 64)
    __shared__ float xsl[NN * 64];     // x-gate slices incl. bias
    __shared__ float hs [8 * DD];      // staged input h rows
    __shared__ float cbuf[2 * 128];    // c ping-pong (block's 16 cols)
    __shared__ float bsl[64];
    __shared__ unsigned stag;

    const int tid  = threadIdx.x;
    const int t    = blockIdx.x >> 4;
    const int dt   = blockIdx.x & 15;
    const int kq   = tid >> 6;         // reduction quarter
    const int w    = tid & 63;         // owned gate-row within tile
    const int gate = w >> 4;
    const int col  = w & 15;
    const int grow = gate * DD + dt * 16 + col;

    if (tid == 0) {
        unsigned G = __hip_atomic_load(&g_gen[t * 16 + dt],
            __ATOMIC_RELAXED, __HIP_MEMORY_SCOPE_AGENT);
        __hip_atomic_store(&g_gen[t * 16 + dt], G + 1u,
            __ATOMIC_RELAXED, __HIP_MEMORY_SCOPE_AGENT);
        stag = G + 1u;
    }
    if (tid < 64) {
        int g2 = tid >> 4, c3 = tid & 15;
        int r2 = g2 * DD + dt * 16 + c3;
        bsl[tid] = bih[r2] + bhh[r2];
    }

    // ---- W_ih + W_hh quarter-rows -> registers (stationary)
    const float4* Wi4 = (const float4*)Wih + (size_t)grow * 64 + kq * 16;
    const float4* Wh4 = (const float4*)Whh + (size_t)grow * 64 + kq * 16;
    float4 wih[16], whh[16];
    #pragma unroll
    for (int j = 0; j < 16; ++j) { wih[j] = Wi4[j]; whh[j] = Wh4[j]; }

    // ---- emb tree rows -> LDS
    const float4* emb4 = (const float4*)emb + (size_t)t * NN * 64;
    float4* es4 = (float4*)es;
    #pragma unroll
    for (int r = 0; r < 8; ++r) {
        int idx = tid + 256 * r;                 // 0..2047, need < 1984
        if (idx < NN * 64) es4[idx] = emb4[idx];
    }
    __syncthreads();
    const unsigned tag = stag;

    // xproj batch [n0, n0+nn), nn <= 8: same fmaf chain / fold order as R10.
    auto xbatch = [&](int n0, int nn) {
        __syncthreads();               // prior epilogue may still read ps
        float acc[8];
        #pragma unroll
        for (int m = 0; m < 8; ++m) acc[m] = 0.f;
        #pragma unroll
        for (int j = 0; j < 16; ++j) {
            float4 wv = wih[j];
            #pragma unroll
            for (int m = 0; m < 8; ++m) {
                if (m < nn) {
                    float4 h = es4[(n0 + m) * 64 + kq * 16 + j];
                    acc[m] = fmaf(wv.x, h.x, fmaf(wv.y, h.y,
                             fmaf(wv.z, h.z, fmaf(wv.w, h.w, acc[m]))));
                }
            }
        }
        #pragma unroll
        for (int m = 0; m < 8; ++m)
            if (m < nn) ps[m * DD + kq * 64 + w] = acc[m];
        __syncthreads();
        #pragma unroll
        for (int rep = 0; rep < 2; ++rep) {
            int idx = tid + 256 * rep;           // 0..511
            if (idx < nn * 64) {
                int m = idx >> 6, w2 = idx & 63;
                xsl[(n0 + m) * 64 + w2] =
                      ps[m * DD +   0 + w2] + ps[m * DD +  64 + w2]
                    + ps[m * DD + 128 + w2] + ps[m * DD + 192 + w2] + bsl[w2];
            }
        }
        __syncthreads();
    };

    // ---- node 0 only, then root: publish h0 ASAP
    xbatch(0, 1);
    if (tid < 16) {
        float xi  = xsl[ 0 + tid];
        float xgg = xsl[32 + tid];
        float xo  = xsl[48 + tid];
        float c0 = sigf(xi) * tanh_f(xgg);        // h(-1)=c(-1)=0
        float h0 = sigf(xo) * tanh_f(c0);
        cbuf[tid] = c0;
        pub64(hx0 + (size_t)t * DD + dt * 16 + tid, tag, h0);
    }

    // ---- deferred work while h0 propagates
    xbatch(1, 6);                      // nodes 1..6 (steps 1-2 children)

    // ---- stage full h0
    {
        const unsigned long long* src = hx0 + (size_t)t * DD;
        unsigned long long v = ld64(src + tid);
        while ((unsigned)(v >> 32) != tag) {
            __builtin_amdgcn_s_sleep(1);
            v = ld64(src + tid);
        }
        hs[tid] = payload(v);
    }
    __syncthreads();

    const unsigned long long* hin[3] = { hx1, hx2, hx3 };
    unsigned long long* hout[3] = { hx1, hx2, hx3 };

    #pragma unroll
    for (int s = 1; s <= 4; ++s) {
        const int L = 1 << (s - 1);              // input rows per tree

        if (s > 1) {
            // poll-stage L full rows; per-word self-validating
            const unsigned long long* src = hin[s - 2] + (size_t)t * L * DD;
            unsigned long long v[8];
            #pragma unroll
            for (int r = 0; r < L; ++r) v[r] = ld64(src + tid + 256 * r);
            #pragma unroll
            for (int r = 0; r < L; ++r) {
                while ((unsigned)(v[r] >> 32) != tag) {
                    __builtin_amdgcn_s_sleep(1);
                    v[r] = ld64(src + tid + 256 * r);
                }
                hs[tid + 256 * r] = payload(v[r]);
            }
            __syncthreads();
        }

        // GEMM: acc[p] = <W_hh[grow] quarter kq, h[p] quarter kq>
        const float4* hs4 = (const float4*)hs;
        float acc[8];
        #pragma unroll
        for (int p = 0; p < 8; ++p) acc[p] = 0.f;
        #pragma unroll
        for (int j = 0; j < 16; ++j) {
            float4 wv = whh[j];
            #pragma unroll
            for (int p = 0; p < L; ++p) {
                float4 h = hs4[p * 64 + kq * 16 + j];    // uniform broadcast
                acc[p] = fmaf(wv.x, h.x, fmaf(wv.y, h.y,
                         fmaf(wv.z, h.z, fmaf(wv.w, h.w, acc[p]))));
            }
        }
        #pragma unroll
        for (int p = 0; p < L; ++p) ps[p * DD + kq * 64 + w] = acc[p];
        __syncthreads();

        // Epilogue: parent p spawns children q=2p,2p+1; publish IMMEDIATELY
        if (tid < 32 * L) {
            const int p  = tid >> 5;
            const int c2 = tid & 15;
            const int q  = tid >> 4;             // child prefix, 0..2L-1
            float g0 = 0.f, g1 = 0.f, g2 = 0.f, g3 = 0.f;
            #pragma unroll
            for (int k = 0; k < 4; ++k) {
                const float* pp = ps + p * DD + k * 64;
                g0 += pp[ 0 + c2]; g1 += pp[16 + c2];
                g2 += pp[32 + c2]; g3 += pp[48 + c2];
            }
            const int node = (1 << s) - 1 + q;
            const float* xp = xsl + node * 64;
            float gi = g0 + xp[ 0 + c2];
            float gf = g1 + xp[16 + c2];
            float gg = g2 + xp[32 + c2];
            float go = g3 + xp[48 + c2];
            float cin = cbuf[((s - 1) & 1) * 128 + p * 16 + c2];
            float cn  = sigf(gf) * cin + sigf(gi) * tanh_f(gg);
            float hn  = sigf(go) * tanh_f(cn);
            if (s < 4) {
                cbuf[(s & 1) * 128 + q * 16 + c2] = cn;
                pub64(hout[s - 1] + (size_t)(t * 2 * L + q) * DD
                                  + dt * 16 + c2, tag, hn);
            } else {
                // launch boundary publishes h4 to the scatter kernel
                h4g[(size_t)(t * NL + q) * DD + dt * 16 + c2] = hn;
            }
        }

        // ---- deferred xproj while this step's h propagates to peers
        if (s == 1)      xbatch( 7, 8);          // nodes  7..14 (step 3)
        else if (s == 2) xbatch(15, 8);          // nodes 15..22 (step 4)
        else if (s == 3) xbatch(23, 8);          // nodes 23..30 (step 4)
    }
}

// ---------------------------------------------------------------------------
// K2: scatter out[b,t,:] = h4[t*16 + argmax(cross[b,t,:]), :]
// 4 rows per wave: cross[16r+l] is CONTIGUOUS, so one wave loads 64 floats
// = 4 complete rows' cross slices (256B coalesced); one ballot yields all 4
// leaves via 16-bit mask groups; 4 row copies with shfl-broadcast indices.
// 2560 blocks (1/4 of the old 10240), same perfectly-coalesced stores.
// ---------------------------------------------------------------------------
__global__ __launch_bounds__(256) void k_scatter(
    const float* __restrict__ cross, const float* __restrict__ htab,
    float* __restrict__ out)
{
    const int tid  = threadIdx.x;
    const int wave = tid >> 6;
    const int lane = tid & 63;
    const int r0 = (blockIdx.x * 4 + wave) * 4;   // first of 4 rows, 0..40956

    // one coalesced load covers cross for rows r0..r0+3
    float v = cross[(size_t)r0 * NL + lane];
    unsigned long long m = __ballot(v > 0.5f);

    // this lane's group g handles row r0+g
    const int g  = lane >> 4;
    const int rr = r0 + g;
    const int b  = rr / NT;
    const int t  = rr - b * NT;
    unsigned mg = (unsigned)(m >> (g * 16)) & 0xFFFFu;
    int leaf = mg ? (int)__builtin_ctz(mg) : 0;
    int p = t * NL + leaf;                        // h4 row for row rr

    const float4* h4 = (const float4*)htab;
    float4* o4 = (float4*)out;

    // copy 4 rows; row it's table index broadcast from lane 16*it
    #pragma unroll
    for (int it = 0; it < 4; ++it) {
        int pit = __shfl(p, it * 16);
        o4[(size_t)(r0 + it) * 64 + lane] = h4[(size_t)pit * 64 + lane];
    }
}

// ---------------------------------------------------------------------------
extern "C" void kernel_launch(void* const* d_in, const int* in_sizes, int n_in,
                              void* d_out, int out_size, void* d_ws, size_t ws_size,
                              hipStream_t stream)
{
    const float* cross = (const float*)d_in[0];
    const float* emb   = (const float*)d_in[1];
    const float* Wih   = (const float*)d_in[2];
    const float* Whh   = (const float*)d_in[3];
    const float* bih   = (const float*)d_in[4];
    const float* bhh   = (const float*)d_in[5];
    float* out = (float*)d_out;

    unsigned long long* hx0 = (unsigned long long*)d_ws;   // 10*256 u64
    unsigned long long* hx1 = hx0 + (size_t)NT * DD;       // 20*256
    unsigned long long* hx2 = hx1 + (size_t)2 * NT * DD;   // 40*256
    unsigned long long* hx3 = hx2 + (size_t)4 * NT * DD;   // 80*256
    float* h4g = (float*)(hx3 + (size_t)8 * NT * DD);      // 160*256 f32

    hipLaunchKernelGGL(k_treelstm, dim3(160), dim3(256), 0, stream,
                       emb, Wih, Whh, bih, bhh, hx0, hx1, hx2, hx3, h4g);
    hipLaunchKernelGGL(k_scatter, dim3(2560), dim3(256), 0, stream,
                       cross, h4g, out);
}